// Round 11
// baseline (355.848 us; speedup 1.0000x reference)
//
#include <hip/hip_runtime.h>

typedef short bf16x8 __attribute__((ext_vector_type(8)));
typedef short bf16x4 __attribute__((ext_vector_type(4)));
typedef float f32x4 __attribute__((ext_vector_type(4)));
typedef float f32x2 __attribute__((ext_vector_type(2)));

#define PS 32        // nodes per partition
#define CAPP 1312    // region capacity: Poisson(1024) + 9 sigma
#define NB 256       // scat-role blocks in mega_k (1024 threads each)
#define CAPB 17536   // bucket staging capacity: Poisson(16327) + ~9.5 sigma
// bucket = 512 nodes = 16 partitions (dst>>9); NBK = ceil(N/512) <= 256

__device__ __forceinline__ unsigned short f2bf(float f) {
    unsigned int u = __float_as_uint(f);
    u = (u + 0x7FFFu + ((u >> 16) & 1u)) >> 16;
    return (unsigned short)u;
}

// ---- mega_k: scatA (blocks 0..NB-1) || unscaled dgemm1 (blocks NB..) ----
// Round-11: h = bf16(x@Wc^T) UNSCALED depends only on x/Wc, so the GEMM runs
// as extra blocks of the scat kernel -- MFMA blocks co-resident with the
// latency-bound scat blocks hide dgemm1's ~50us entirely (multi-stream is
// banned under graph capture; block-role split is the only overlap primitive).
// Scat role: histogram by bucket + coalesced bucket-run scatter of
// (src | node_local<<17, w); blocks 0..7 also pre-convert Wf/W2 to bf16.
// GEMM role: 256 rows/block, per-block Wc fp32->bf16 conversion (L2-resident).
__global__ __launch_bounds__(1024) void mega_k(const int* __restrict__ ei,
                                               const float* __restrict__ ew,
                                               int* __restrict__ bucketCnt,
                                               int2* __restrict__ bstage,
                                               const float* __restrict__ x,
                                               const float* __restrict__ Wc,
                                               const float* __restrict__ Wf,
                                               const float* __restrict__ W2,
                                               unsigned short* __restrict__ wfb,
                                               unsigned short* __restrict__ w2b,
                                               unsigned short* __restrict__ h,
                                               int E, int M, int NBK, int EPB) {
    __shared__ __align__(16) unsigned short Wl[128 * 136];  // scat reuses as cntl/basel
    const int b = blockIdx.x, tid = threadIdx.x;

    if (b < NB) {
        // ================= scat role =================
        int* cntl = (int*)Wl;
        int* basel = cntl + 256;
        if (b < 8) {  // wfb/w2b prep: 8192 float4 chunks = 2 x 16384 elems
            int t = (b << 10) | tid;
            int a = t >> 12, idx = t & 4095;
            const float4* s4 = (const float4*)(a == 0 ? Wf : W2);
            unsigned short* dw = (a == 0 ? wfb : w2b);
            float4 v = s4[idx];
            ushort4 o;
            o.x = f2bf(v.x); o.y = f2bf(v.y); o.z = f2bf(v.z); o.w = f2bf(v.w);
            *(ushort4*)(dw + idx * 4) = o;
        }
        if (tid < 256) cntl[tid] = 0;
        __syncthreads();
        const int s = b * EPB, e = min(E, s + EPB);
        for (int i = s + tid; i < e; i += 1024)
            atomicAdd(&cntl[ei[E + i] >> 9], 1);
        __syncthreads();
        if (tid < NBK) {
            int c = cntl[tid];
            basel[tid] = tid * CAPB + (c ? atomicAdd(&bucketCnt[tid], c) : 0);
            cntl[tid] = 0;
        }
        __syncthreads();
        for (int i = s + tid; i < e; i += 1024) {
            int src = ei[i];          // cold read
            int dst = ei[E + i];      // L2-hot (read in phase 1)
            float w = ew[i];
            int bk = dst >> 9;
            int lidx = atomicAdd(&cntl[bk], 1);
            int pos = basel[bk] + lidx;
            if (pos < (bk + 1) * CAPB)  // overflow guard: statistically never
                bstage[pos] = make_int2(src | ((dst & 511) << 17), __float_as_int(w));
        }
    } else {
        // ================= gemm role: h' = bf16(x@Wc^T), 256 rows =================
        const int gb = b - NB;
        // stage Wc fp32 -> bf16 into Wl (136-stride)
#pragma unroll
        for (int i = 0; i < 4; ++i) {
            int e4 = i * 1024 + tid;
            float4 v = ((const float4*)Wc)[e4];
            int el = e4 * 4, r = el >> 7, cc = el & 127;
            unsigned short* pp = &Wl[r * 136 + cc];
            pp[0] = f2bf(v.x); pp[1] = f2bf(v.y); pp[2] = f2bf(v.z); pp[3] = f2bf(v.w);
        }
        __syncthreads();

        const int wave = tid >> 6, lane = tid & 63;
        const int m = lane & 15, quad = lane >> 4;
        const int rowBase = gb * 256 + wave * 16;
        if (rowBase < M) {  // per-wave skip; no barriers below
            int arow = rowBase + m;
            int arowc = arow < M ? arow : (M - 1);

            bf16x8 afrag[4];
            const float* pa = x + (size_t)arowc * 128 + quad * 8;
#pragma unroll
            for (int kc = 0; kc < 4; ++kc) {
                float4 v0 = *(const float4*)(pa + kc * 32);
                float4 v1 = *(const float4*)(pa + kc * 32 + 4);
                bf16x8 f;
                f[0] = (short)f2bf(v0.x); f[1] = (short)f2bf(v0.y);
                f[2] = (short)f2bf(v0.z); f[3] = (short)f2bf(v0.w);
                f[4] = (short)f2bf(v1.x); f[5] = (short)f2bf(v1.y);
                f[6] = (short)f2bf(v1.z); f[7] = (short)f2bf(v1.w);
                afrag[kc] = f;
            }

#pragma unroll
            for (int nt = 0; nt < 8; ++nt) {
                f32x4 acc = {0.f, 0.f, 0.f, 0.f};
                const unsigned short* wb = &Wl[(nt * 16 + m) * 136 + quad * 8];
#pragma unroll
                for (int kc = 0; kc < 4; ++kc) {
                    bf16x8 bfrag = *(const bf16x8*)(wb + kc * 32);
                    acc = __builtin_amdgcn_mfma_f32_16x16x32_bf16(afrag[kc], bfrag, acc, 0, 0, 0);
                }
                const int col = nt * 16 + m;
#pragma unroll
                for (int r = 0; r < 4; ++r) {
                    int row = rowBase + quad * 4 + r;
                    if (row < M)  // channel-split store: h[col>>6][row][col&63]
                        h[((size_t)(col >> 6) * M + row) * 64 + (col & 63)] = f2bf(acc[r]);
                }
            }
        }
    }
}

// ---- scatB: edge bookkeeping (node counts -> dinv/nodeOff/partCnt) +
//      COALESCING partition-cursor placement (round-9 style) ----
// Round-11: round-10's node-sorted placement reverted (64 stores/wave to 64
// distinct lines cost ~25-30us; node-sorting bought nothing since aggF is
// gather-bound). Partition cursors make concurrent same-partition stores
// adjacent -> intra-line coalescing.
__global__ __launch_bounds__(1024) void scatB_k(const int* __restrict__ bucketCnt,
                                                const int2* __restrict__ bstage,
                                                int* __restrict__ partCnt,
                                                int* __restrict__ nodeOff,
                                                float* __restrict__ dinv,
                                                int2* __restrict__ regions,
                                                int P, int N) {
    __shared__ int cnode[512];
    __shared__ float degf[512];
    __shared__ int cur[16];
    const int bk = blockIdx.x, tid = threadIdx.x;
    const int cnt = min(bucketCnt[bk], CAPB);
    const int2* bs = bstage + (size_t)bk * CAPB;

    if (tid < 512) { cnode[tid] = 0; degf[tid] = 0.f; }
    if (tid < 16) cur[tid] = 0;
    __syncthreads();
    for (int i = tid; i < cnt; i += 1024) {
        int2 r = bs[i];
        int nl = ((unsigned)r.x >> 17) & 511;
        atomicAdd(&cnode[nl], 1);
        atomicAdd(&degf[nl], __int_as_float(r.y));
    }
    __syncthreads();
    if (tid < 512) {  // per-partition (32-node segment) exclusive scan
        int cn = cnode[tid];
        int v = cn;
#pragma unroll
        for (int off = 1; off < 32; off <<= 1) {
            int u = __shfl_up(v, off, 32);
            if ((tid & 31) >= off) v += u;
        }
        int n = bk * 512 + tid;
        if (n < N) {
            nodeOff[n] = v - cn;
            dinv[n] = rsqrtf(1.0f + degf[tid]);  // self-loop weight 1
        }
        if ((tid & 31) == 31) {
            int p = bk * 16 + (tid >> 5);
            if (p < P) partCnt[p] = v;
        }
    }
    __syncthreads();
    for (int i = tid; i < cnt; i += 1024) {
        int2 r = bs[i];
        unsigned xx = (unsigned)r.x;
        int nl = (xx >> 17) & 511;
        int pl = nl >> 5;
        int pos = atomicAdd(&cur[pl], 1);
        if (pos < CAPP) {
            int p = bk * 16 + pl;
            regions[(size_t)p * CAPP + pos] =
                make_int2((int)(xx & 0x1FFFFu) | ((nl & 31) << 24), r.y);
        }
    }
}

// ---- aggF: LDS counting-sort with dinv[src] fold + gather-reduce ----
// h2[n] = bf16(relu( dinv[n]*sum(w*dinv[src]*h[src]) + dinv[n]^2*h[n] + b_conv ))
// h is UNSCALED (mega-kernel); dinv[src] (400KB, L2-resident) folded into the
// staged weight during the sort pass. Gather loop = proven local-roofline form.
__global__ __launch_bounds__(256) void aggF_k(const int* __restrict__ partCnt,
                                              const int* __restrict__ nodeOff,
                                              const int2* __restrict__ regions,
                                              const unsigned short* __restrict__ h,
                                              const float* __restrict__ dinv,
                                              const float* __restrict__ bconv,
                                              unsigned short* __restrict__ h2, int N) {
    __shared__ __align__(16) int2 stag[CAPP];
    __shared__ int cstart[PS + 1];
    __shared__ int wcur[PS];
    const int p = blockIdx.x, tid = threadIdx.x;
    const int cnt = min(partCnt[p], CAPP);
    const int2* reg = regions + (size_t)p * CAPP;

    if (tid < PS) {
        int node = p * PS + tid;
        int o = (node < N) ? nodeOff[node] : cnt;
        cstart[tid] = o;
        wcur[tid] = o;
    } else if (tid == PS) {
        cstart[PS] = cnt;
    }
    __syncthreads();
    // sort pass: pre-shift src to byte offset; fold dinv[src] into the weight
    for (int i = tid; i < cnt; i += 256) {
        int2 r = reg[i];
        unsigned xx = (unsigned)r.x;
        int srcn = xx & 0xFFFFFF;
        int pos = atomicAdd(&wcur[(xx >> 24) & 31], 1);
        stag[pos] = make_int2(srcn << 7,
                              __float_as_int(__int_as_float(r.y) * dinv[srcn]));
    }
    __syncthreads();

    const int wave = tid >> 6, lane = tid & 63;
    const int g = lane >> 4;              // edge slot 0..3
    const int c4 = (lane & 15) * 4;       // channel base within the 64-ch half
    const int c4b = c4 * 2;               // ...as bytes

#define ACC2(q, w) {                                                        \
        unsigned ux = (unsigned)(q).x, uy = (unsigned)(q).y;                \
        f32x2 ww; ww[0] = (w); ww[1] = (w);                                 \
        f32x2 v01, v23;                                                     \
        v01[0] = __uint_as_float(ux << 16);                                 \
        v01[1] = __uint_as_float(ux & 0xFFFF0000u);                         \
        v23[0] = __uint_as_float(uy << 16);                                 \
        v23[1] = __uint_as_float(uy & 0xFFFF0000u);                         \
        a01 = v01 * ww + a01; a23 = v23 * ww + a23; }

#pragma unroll
    for (int hh = 0; hh < 2; ++hh) {
        const char* hb = (const char*)h + ((size_t)hh * (size_t)N << 7);
        for (int nl = wave; nl < PS; nl += 4) {
            int n = p * PS + nl;
            if (n >= N) continue;
            const int s = cstart[nl], e = cstart[nl + 1];
            f32x2 a01 = {0.f, 0.f}, a23 = {0.f, 0.f};
            int j = s;
            const int e32 = s + ((e - s) & ~31);
            for (; j < e32; j += 32) {
                int2 r0 = stag[j + g];
                int2 r1 = stag[j + 4 + g];
                int2 r2 = stag[j + 8 + g];
                int2 r3 = stag[j + 12 + g];
                int2 r4 = stag[j + 16 + g];
                int2 r5 = stag[j + 20 + g];
                int2 r6 = stag[j + 24 + g];
                int2 r7 = stag[j + 28 + g];
                int2 q0 = *(const int2*)(hb + ((unsigned)r0.x + c4b));
                int2 q1 = *(const int2*)(hb + ((unsigned)r1.x + c4b));
                int2 q2 = *(const int2*)(hb + ((unsigned)r2.x + c4b));
                int2 q3 = *(const int2*)(hb + ((unsigned)r3.x + c4b));
                int2 q4 = *(const int2*)(hb + ((unsigned)r4.x + c4b));
                int2 q5 = *(const int2*)(hb + ((unsigned)r5.x + c4b));
                int2 q6 = *(const int2*)(hb + ((unsigned)r6.x + c4b));
                int2 q7 = *(const int2*)(hb + ((unsigned)r7.x + c4b));
                ACC2(q0, __int_as_float(r0.y));
                ACC2(q1, __int_as_float(r1.y));
                ACC2(q2, __int_as_float(r2.y));
                ACC2(q3, __int_as_float(r3.y));
                ACC2(q4, __int_as_float(r4.y));
                ACC2(q5, __int_as_float(r5.y));
                ACC2(q6, __int_as_float(r6.y));
                ACC2(q7, __int_as_float(r7.y));
            }
            const int e16 = s + ((e - s) & ~15);
            for (; j < e16; j += 16) {
                int2 r0 = stag[j + g];
                int2 r1 = stag[j + 4 + g];
                int2 r2 = stag[j + 8 + g];
                int2 r3 = stag[j + 12 + g];
                int2 q0 = *(const int2*)(hb + ((unsigned)r0.x + c4b));
                int2 q1 = *(const int2*)(hb + ((unsigned)r1.x + c4b));
                int2 q2 = *(const int2*)(hb + ((unsigned)r2.x + c4b));
                int2 q3 = *(const int2*)(hb + ((unsigned)r3.x + c4b));
                ACC2(q0, __int_as_float(r0.y));
                ACC2(q1, __int_as_float(r1.y));
                ACC2(q2, __int_as_float(r2.y));
                ACC2(q3, __int_as_float(r3.y));
            }
            for (; j < e; j += 8) {
                int j0 = j + g, j1 = j + 4 + g;
                int2 r0 = stag[j0 < e ? j0 : s];
                int2 r1 = stag[j1 < e ? j1 : s];
                float w0 = (j0 < e) ? __int_as_float(r0.y) : 0.f;
                float w1 = (j1 < e) ? __int_as_float(r1.y) : 0.f;
                int2 q0 = *(const int2*)(hb + ((unsigned)r0.x + c4b));
                int2 q1 = *(const int2*)(hb + ((unsigned)r1.x + c4b));
                ACC2(q0, w0);
                ACC2(q1, w1);
            }
            float acc[4] = {a01[0], a01[1], a23[0], a23[1]};
#pragma unroll
            for (int k = 0; k < 4; ++k) {
                float v = acc[k];
                v += __shfl_xor(v, 16, 64);
                v += __shfl_xor(v, 32, 64);
                acc[k] = v;
            }
            if (g == 0) {
                float di = dinv[n];
                float sc = di * di;  // self-loop: dinv[n]*1*dinv[n]*h[n]
                int2 qs = *(const int2*)(hb + (((size_t)(unsigned)n << 7) + c4b));
                float4 b = *(const float4*)(bconv + hh * 64 + c4);
                unsigned ux = (unsigned)qs.x, uy = (unsigned)qs.y;
                bf16x4 o;
                o[0] = (short)f2bf(fmaxf(di * acc[0] + sc * __uint_as_float(ux << 16) + b.x, 0.f));
                o[1] = (short)f2bf(fmaxf(di * acc[1] + sc * __uint_as_float(ux & 0xFFFF0000u) + b.y, 0.f));
                o[2] = (short)f2bf(fmaxf(di * acc[2] + sc * __uint_as_float(uy << 16) + b.z, 0.f));
                o[3] = (short)f2bf(fmaxf(di * acc[3] + sc * __uint_as_float(uy & 0xFFFF0000u) + b.w, 0.f));
                *(bf16x4*)(h2 + (size_t)n * 128 + hh * 64 + c4) = o;
            }
        }
    }
#undef ACC2
}

// ---- gemm23: out = relu(h2 @ Wf^T + bf) @ W2^T + b2, intermediate staged in LDS ----
__global__ __launch_bounds__(256) void gemm23_k(const unsigned short* __restrict__ h2,
                                                const unsigned short* __restrict__ Wfb,
                                                const float* __restrict__ bfc,
                                                const unsigned short* __restrict__ W2b,
                                                const float* __restrict__ b2,
                                                float* __restrict__ out, int M) {
    __shared__ __align__(16) unsigned short Wl[128 * 136];
    __shared__ __align__(16) unsigned short Tl[64 * 136];
    const int tid = threadIdx.x;

    // stage Wfb (bf16 dense) -> Wl (136-stride)
#pragma unroll
    for (int i = 0; i < 8; ++i) {
        int c = i * 256 + tid;
        int r = c >> 4, col = (c & 15) * 8;
        *(bf16x8*)&Wl[r * 136 + col] = *(const bf16x8*)(Wfb + c * 8);
    }
    __syncthreads();

    const int wave = tid >> 6, lane = tid & 63;
    const int m = lane & 15, quad = lane >> 4;
    const int rowBase = blockIdx.x * 64 + wave * 16;
    int arow = rowBase + m;
    int arowc = arow < M ? arow : (M - 1);

    bf16x8 afrag[4];
    {
        const unsigned short* pa = h2 + (size_t)arowc * 128 + quad * 8;
#pragma unroll
        for (int kc = 0; kc < 4; ++kc)
            afrag[kc] = *(const bf16x8*)(pa + kc * 32);
    }

    // stage 1: T = bf16(relu(h2 @ Wf^T + bf)) -> LDS
#pragma unroll
    for (int nt = 0; nt < 8; ++nt) {
        f32x4 acc = {0.f, 0.f, 0.f, 0.f};
        const unsigned short* wb = &Wl[(nt * 16 + m) * 136 + quad * 8];
#pragma unroll
        for (int kc = 0; kc < 4; ++kc) {
            bf16x8 bfrag = *(const bf16x8*)(wb + kc * 32);
            acc = __builtin_amdgcn_mfma_f32_16x16x32_bf16(afrag[kc], bfrag, acc, 0, 0, 0);
        }
        const int col = nt * 16 + m;
        float bv = bfc[col];
#pragma unroll
        for (int r = 0; r < 4; ++r) {
            int rowl = wave * 16 + quad * 4 + r;
            Tl[rowl * 136 + col] = f2bf(fmaxf(acc[r] + bv, 0.f));
        }
    }
    __syncthreads();

    // stage W2b (overwrite Wl)
#pragma unroll
    for (int i = 0; i < 8; ++i) {
        int c = i * 256 + tid;
        int r = c >> 4, col = (c & 15) * 8;
        *(bf16x8*)&Wl[r * 136 + col] = *(const bf16x8*)(W2b + c * 8);
    }
    __syncthreads();

    // stage 2: out = T @ W2^T + b2
    bf16x8 afrag2[4];
    {
        const unsigned short* pa = &Tl[(wave * 16 + m) * 136 + quad * 8];
#pragma unroll
        for (int kc = 0; kc < 4; ++kc)
            afrag2[kc] = *(const bf16x8*)(pa + kc * 32);
    }
#pragma unroll
    for (int nt = 0; nt < 8; ++nt) {
        f32x4 acc = {0.f, 0.f, 0.f, 0.f};
        const unsigned short* wb = &Wl[(nt * 16 + m) * 136 + quad * 8];
#pragma unroll
        for (int kc = 0; kc < 4; ++kc) {
            bf16x8 bfrag = *(const bf16x8*)(wb + kc * 32);
            acc = __builtin_amdgcn_mfma_f32_16x16x32_bf16(afrag2[kc], bfrag, acc, 0, 0, 0);
        }
        const int col = nt * 16 + m;
        float bv = b2[col];
#pragma unroll
        for (int r = 0; r < 4; ++r) {
            int row = rowBase + quad * 4 + r;
            if (row < M)
                out[(size_t)row * 128 + col] = acc[r] + bv;
        }
    }
}

extern "C" void kernel_launch(void* const* d_in, const int* in_sizes, int n_in,
                              void* d_out, int out_size, void* d_ws, size_t ws_size,
                              hipStream_t stream) {
    const float* x  = (const float*)d_in[0];
    const int* ei   = (const int*)d_in[1];
    const float* ew = (const float*)d_in[2];
    const float* Wc = (const float*)d_in[3];
    const float* bc = (const float*)d_in[4];
    const float* Wf = (const float*)d_in[5];
    const float* bf = (const float*)d_in[6];
    const float* W2 = (const float*)d_in[7];
    const float* b2 = (const float*)d_in[8];
    float* out = (float*)d_out;

    const int N = in_sizes[0] / 128;
    const int E = in_sizes[2];
    const int P = (N + PS - 1) / PS;     // 3125
    const int NBK = (N + 511) >> 9;      // 196 buckets of 16 partitions

    auto align256 = [](size_t v) { return (v + 255) & ~(size_t)255; };
    char* ws = (char*)d_ws;
    size_t off = 0;
    float* dinv  = (float*)(ws + off); off += align256((size_t)N * 4);
    int* nodeOff = (int*)(ws + off);   off += align256((size_t)N * 4);
    int* partCnt = (int*)(ws + off);   off += align256((size_t)P * 4);
    int* bucketCnt = (int*)(ws + off); off += align256((size_t)NBK * 4);
    unsigned short* wfb = (unsigned short*)(ws + off); off += align256(16384 * 2);
    unsigned short* w2b = (unsigned short*)(ws + off); off += align256(16384 * 2);
    unsigned short* h  = (unsigned short*)(ws + off); off += (size_t)N * 256;  // h'[2][N][64] channel-split (own buffer: written concurrently with bstage)
    // h2 and bstage share a slot: bstage (27.5MB) is consumed by scatB before
    // aggF writes h2 (25.6MB). Slot sized to the max of the two.
    unsigned short* h2 = (unsigned short*)(ws + off);
    int2* bstage = (int2*)(ws + off);

    // d_out scratch: partition regions P*CAPP*8B = 32.8MB <= 51.2MB,
    // consumed by aggF before gemm23 rewrites d_out.
    int2* regions = (int2*)out;

    const int EPB = (E + NB - 1) / NB;
    const int GB = (N + 255) / 256;      // gemm-role blocks in mega_k

    hipMemsetAsync(bucketCnt, 0, (size_t)NBK * 4, stream);
    mega_k<<<NB + GB, 1024, 0, stream>>>(ei, ew, bucketCnt, bstage, x, Wc, Wf, W2,
                                         wfb, w2b, h, E, N, NBK, EPB);
    scatB_k<<<NBK, 1024, 0, stream>>>(bucketCnt, bstage, partCnt, nodeOff, dinv, regions, P, N);
    aggF_k<<<P, 256, 0, stream>>>(partCnt, nodeOff, regions, h, dinv, bc, h2, N);
    gemm23_k<<<(N + 63) / 64, 256, 0, stream>>>(h2, wfb, bf, w2b, b2, out, N);
}

// Round 12
// 342.684 us; speedup vs baseline: 1.0384x; 1.0384x over previous
//
#include <hip/hip_runtime.h>

typedef short bf16x8 __attribute__((ext_vector_type(8)));
typedef short bf16x4 __attribute__((ext_vector_type(4)));
typedef float f32x4 __attribute__((ext_vector_type(4)));
typedef float f32x2 __attribute__((ext_vector_type(2)));

#define PS 32        // nodes per partition
#define CAPP 1312    // region capacity: Poisson(1024) + 9 sigma
#define NB 256       // scatA blocks (1024 threads each)
#define CAPB 17536   // bucket staging capacity: Poisson(16327) + ~9.5 sigma
// bucket = 512 nodes = 16 partitions (dst>>9); NBK = ceil(N/512) <= 256

__device__ __forceinline__ unsigned short f2bf(float f) {
    unsigned int u = __float_as_uint(f);
    u = (u + 0x7FFFu + ((u >> 16) & 1u)) >> 16;
    return (unsigned short)u;
}

// ---- scatA: histogram by bucket + coalesced bucket-run scatter + weight prep ----
// Round-12: standalone again (round-11 mega-fusion dropped — it saved 5.5us on
// the scat side but forced unscaled h -> dinv fold in aggF's sort = +24us).
// Staging entry packs src(17b) | node_local(9b)<<17.
__global__ __launch_bounds__(1024) void scatA_k(const int* __restrict__ ei,
                                                const float* __restrict__ ew,
                                                int* __restrict__ bucketCnt,
                                                int2* __restrict__ bstage,
                                                const float* __restrict__ Wc,
                                                const float* __restrict__ Wf,
                                                const float* __restrict__ W2,
                                                unsigned short* __restrict__ wcb,
                                                unsigned short* __restrict__ wfb,
                                                unsigned short* __restrict__ w2b,
                                                int E, int NBK, int EPB) {
    __shared__ int cntl[256];
    __shared__ int basel[256];
    const int b = blockIdx.x, tid = threadIdx.x;

    if (b < 12) {  // weight prep: 12288 float4 chunks = 3 x 16384 elems
        int t = (b << 10) | tid;
        int a = t >> 12, idx = t & 4095;
        const float4* s4 = (const float4*)(a == 0 ? Wc : (a == 1 ? Wf : W2));
        unsigned short* dw = (a == 0 ? wcb : (a == 1 ? wfb : w2b));
        float4 v = s4[idx];
        ushort4 o;
        o.x = f2bf(v.x); o.y = f2bf(v.y); o.z = f2bf(v.z); o.w = f2bf(v.w);
        *(ushort4*)(dw + idx * 4) = o;
    }

    if (tid < 256) cntl[tid] = 0;
    __syncthreads();
    const int s = b * EPB, e = min(E, s + EPB);
    for (int i = s + tid; i < e; i += 1024)
        atomicAdd(&cntl[ei[E + i] >> 9], 1);
    __syncthreads();
    if (tid < NBK) {
        int c = cntl[tid];
        basel[tid] = tid * CAPB + (c ? atomicAdd(&bucketCnt[tid], c) : 0);
        cntl[tid] = 0;
    }
    __syncthreads();
    for (int i = s + tid; i < e; i += 1024) {
        int src = ei[i];          // cold read
        int dst = ei[E + i];      // L2-hot (read in phase 1)
        float w = ew[i];
        int bk = dst >> 9;
        int lidx = atomicAdd(&cntl[bk], 1);
        int pos = basel[bk] + lidx;
        if (pos < (bk + 1) * CAPB)  // overflow guard: statistically never
            bstage[pos] = make_int2(src | ((dst & 511) << 17), __float_as_int(w));
    }
}

// ---- scatB: edge bookkeeping (node counts -> dinv/nodeOff/partCnt) +
//      coalescing partition-cursor placement ----
// Owns ALL bookkeeping (deletes dgemm1's 32.8MB regions re-read + 6.4M LDS
// atomics). Cursor placement keeps concurrent same-partition stores adjacent
// (round-10's node-sorted placement cost ~25us of store scatter for zero
// aggF gain — aggF is gather-bound, conflicts were off the critical path).
__global__ __launch_bounds__(1024) void scatB_k(const int* __restrict__ bucketCnt,
                                                const int2* __restrict__ bstage,
                                                int* __restrict__ partCnt,
                                                int* __restrict__ nodeOff,
                                                float* __restrict__ dinv,
                                                int2* __restrict__ regions,
                                                int P, int N) {
    __shared__ int cnode[512];
    __shared__ float degf[512];
    __shared__ int cur[16];
    const int bk = blockIdx.x, tid = threadIdx.x;
    const int cnt = min(bucketCnt[bk], CAPB);
    const int2* bs = bstage + (size_t)bk * CAPB;

    if (tid < 512) { cnode[tid] = 0; degf[tid] = 0.f; }
    if (tid < 16) cur[tid] = 0;
    __syncthreads();
    for (int i = tid; i < cnt; i += 1024) {
        int2 r = bs[i];
        int nl = ((unsigned)r.x >> 17) & 511;
        atomicAdd(&cnode[nl], 1);
        atomicAdd(&degf[nl], __int_as_float(r.y));
    }
    __syncthreads();
    if (tid < 512) {  // per-partition (32-node segment) exclusive scan
        int cn = cnode[tid];
        int v = cn;
#pragma unroll
        for (int off = 1; off < 32; off <<= 1) {
            int u = __shfl_up(v, off, 32);
            if ((tid & 31) >= off) v += u;
        }
        int n = bk * 512 + tid;
        if (n < N) {
            nodeOff[n] = v - cn;
            dinv[n] = rsqrtf(1.0f + degf[tid]);  // self-loop weight 1
        }
        if ((tid & 31) == 31) {
            int p = bk * 16 + (tid >> 5);
            if (p < P) partCnt[p] = v;
        }
    }
    __syncthreads();
    for (int i = tid; i < cnt; i += 1024) {
        int2 r = bs[i];
        unsigned xx = (unsigned)r.x;
        int nl = (xx >> 17) & 511;
        int pl = nl >> 5;
        int pos = atomicAdd(&cur[pl], 1);
        if (pos < CAPP) {
            int p = bk * 16 + pl;
            regions[(size_t)p * CAPP + pos] =
                make_int2((int)(xx & 0x1FFFFu) | ((nl & 31) << 24), r.y);
        }
    }
}

// ---- dgemm1: pure streaming GEMM h' = bf16(dinv .* x@Wc^T), channel-split ----
// No regions read, no LDS atomics (scatB owns bookkeeping). 64-row blocks.
__global__ __launch_bounds__(256) void dgemm1_k(const float* __restrict__ x,
                                                const unsigned short* __restrict__ Wcb,
                                                const float* __restrict__ dinv,
                                                unsigned short* __restrict__ h,
                                                int M) {
    __shared__ __align__(16) unsigned short Wl[128 * 136];
    __shared__ float dl64[64];
    const int tid = threadIdx.x;

    if (tid < 64) {
        int node = blockIdx.x * 64 + tid;
        dl64[tid] = (node < M) ? dinv[node] : 0.f;
    }

    // stage Wcb (bf16 dense) -> Wl (136-stride); no conversion
#pragma unroll
    for (int i = 0; i < 8; ++i) {
        int c = i * 256 + tid;
        int r = c >> 4, col = (c & 15) * 8;
        *(bf16x8*)&Wl[r * 136 + col] = *(const bf16x8*)(Wcb + c * 8);
    }
    __syncthreads();

    const int wave = tid >> 6, lane = tid & 63;
    const int m = lane & 15, quad = lane >> 4;
    const int rowBase = blockIdx.x * 64 + wave * 16;
    int arow = rowBase + m;
    int arowc = arow < M ? arow : (M - 1);

    bf16x8 afrag[4];
    const float* pa = x + (size_t)arowc * 128 + quad * 8;
#pragma unroll
    for (int kc = 0; kc < 4; ++kc) {
        float4 v0 = *(const float4*)(pa + kc * 32);
        float4 v1 = *(const float4*)(pa + kc * 32 + 4);
        bf16x8 f;
        f[0] = (short)f2bf(v0.x); f[1] = (short)f2bf(v0.y);
        f[2] = (short)f2bf(v0.z); f[3] = (short)f2bf(v0.w);
        f[4] = (short)f2bf(v1.x); f[5] = (short)f2bf(v1.y);
        f[6] = (short)f2bf(v1.z); f[7] = (short)f2bf(v1.w);
        afrag[kc] = f;
    }

    float dv[4];
#pragma unroll
    for (int r = 0; r < 4; ++r)
        dv[r] = dl64[wave * 16 + quad * 4 + r];

#pragma unroll
    for (int nt = 0; nt < 8; ++nt) {
        f32x4 acc = {0.f, 0.f, 0.f, 0.f};
        const unsigned short* wb = &Wl[(nt * 16 + m) * 136 + quad * 8];
#pragma unroll
        for (int kc = 0; kc < 4; ++kc) {
            bf16x8 bfrag = *(const bf16x8*)(wb + kc * 32);
            acc = __builtin_amdgcn_mfma_f32_16x16x32_bf16(afrag[kc], bfrag, acc, 0, 0, 0);
        }
        const int col = nt * 16 + m;
#pragma unroll
        for (int r = 0; r < 4; ++r) {
            int row = rowBase + quad * 4 + r;
            if (row < M)  // channel-split store: h[col>>6][row][col&63]
                h[((size_t)(col >> 6) * M + row) * 64 + (col & 63)] = f2bf(acc[r] * dv[r]);
        }
    }
}

// ---- aggF: LDS counting-sort (offsets from scatB) + gather-reduce ----
// h2[n] = bf16(relu( dinv[n]*( sum w*h'[src] + h'[n] ) + b_conv ))
// Proven round-9 form (103.3us, FETCH 325MB, VGPR 32): no dinv fold in the
// sort pass (twice-measured at +11/+24us — rounds 5 and 11).
__global__ __launch_bounds__(256) void aggF_k(const int* __restrict__ partCnt,
                                              const int* __restrict__ nodeOff,
                                              const int2* __restrict__ regions,
                                              const unsigned short* __restrict__ h,
                                              const float* __restrict__ dinv,
                                              const float* __restrict__ bconv,
                                              unsigned short* __restrict__ h2, int N) {
    __shared__ __align__(16) int2 stag[CAPP];
    __shared__ int cstart[PS + 1];
    __shared__ int wcur[PS];
    const int p = blockIdx.x, tid = threadIdx.x;
    const int cnt = min(partCnt[p], CAPP);
    const int2* reg = regions + (size_t)p * CAPP;

    if (tid < PS) {
        int node = p * PS + tid;
        int o = (node < N) ? nodeOff[node] : cnt;
        cstart[tid] = o;
        wcur[tid] = o;
    } else if (tid == PS) {
        cstart[PS] = cnt;
    }
    __syncthreads();
    // sort pass: pre-shift src index into the byte offset of its 128B half-line
    for (int i = tid; i < cnt; i += 256) {
        int2 r = reg[i];
        int pos = atomicAdd(&wcur[(r.x >> 24) & 31], 1);
        stag[pos] = make_int2((r.x & 0xFFFFFF) << 7, r.y);
    }
    __syncthreads();

    const int wave = tid >> 6, lane = tid & 63;
    const int g = lane >> 4;              // edge slot 0..3
    const int c4 = (lane & 15) * 4;       // channel base within the 64-ch half
    const int c4b = c4 * 2;               // ...as bytes

#define ACC2(q, w) {                                                        \
        unsigned ux = (unsigned)(q).x, uy = (unsigned)(q).y;                \
        f32x2 ww; ww[0] = (w); ww[1] = (w);                                 \
        f32x2 v01, v23;                                                     \
        v01[0] = __uint_as_float(ux << 16);                                 \
        v01[1] = __uint_as_float(ux & 0xFFFF0000u);                         \
        v23[0] = __uint_as_float(uy << 16);                                 \
        v23[1] = __uint_as_float(uy & 0xFFFF0000u);                         \
        a01 = v01 * ww + a01; a23 = v23 * ww + a23; }

#pragma unroll
    for (int hh = 0; hh < 2; ++hh) {
        const char* hb = (const char*)h + ((size_t)hh * (size_t)N << 7);
        for (int nl = wave; nl < PS; nl += 4) {
            int n = p * PS + nl;
            if (n >= N) continue;
            const int s = cstart[nl], e = cstart[nl + 1];
            f32x2 a01 = {0.f, 0.f}, a23 = {0.f, 0.f};
            int j = s;
            const int e32 = s + ((e - s) & ~31);
            for (; j < e32; j += 32) {
                int2 r0 = stag[j + g];
                int2 r1 = stag[j + 4 + g];
                int2 r2 = stag[j + 8 + g];
                int2 r3 = stag[j + 12 + g];
                int2 r4 = stag[j + 16 + g];
                int2 r5 = stag[j + 20 + g];
                int2 r6 = stag[j + 24 + g];
                int2 r7 = stag[j + 28 + g];
                int2 q0 = *(const int2*)(hb + ((unsigned)r0.x + c4b));
                int2 q1 = *(const int2*)(hb + ((unsigned)r1.x + c4b));
                int2 q2 = *(const int2*)(hb + ((unsigned)r2.x + c4b));
                int2 q3 = *(const int2*)(hb + ((unsigned)r3.x + c4b));
                int2 q4 = *(const int2*)(hb + ((unsigned)r4.x + c4b));
                int2 q5 = *(const int2*)(hb + ((unsigned)r5.x + c4b));
                int2 q6 = *(const int2*)(hb + ((unsigned)r6.x + c4b));
                int2 q7 = *(const int2*)(hb + ((unsigned)r7.x + c4b));
                ACC2(q0, __int_as_float(r0.y));
                ACC2(q1, __int_as_float(r1.y));
                ACC2(q2, __int_as_float(r2.y));
                ACC2(q3, __int_as_float(r3.y));
                ACC2(q4, __int_as_float(r4.y));
                ACC2(q5, __int_as_float(r5.y));
                ACC2(q6, __int_as_float(r6.y));
                ACC2(q7, __int_as_float(r7.y));
            }
            const int e16 = s + ((e - s) & ~15);
            for (; j < e16; j += 16) {
                int2 r0 = stag[j + g];
                int2 r1 = stag[j + 4 + g];
                int2 r2 = stag[j + 8 + g];
                int2 r3 = stag[j + 12 + g];
                int2 q0 = *(const int2*)(hb + ((unsigned)r0.x + c4b));
                int2 q1 = *(const int2*)(hb + ((unsigned)r1.x + c4b));
                int2 q2 = *(const int2*)(hb + ((unsigned)r2.x + c4b));
                int2 q3 = *(const int2*)(hb + ((unsigned)r3.x + c4b));
                ACC2(q0, __int_as_float(r0.y));
                ACC2(q1, __int_as_float(r1.y));
                ACC2(q2, __int_as_float(r2.y));
                ACC2(q3, __int_as_float(r3.y));
            }
            for (; j < e; j += 8) {
                int j0 = j + g, j1 = j + 4 + g;
                int2 r0 = stag[j0 < e ? j0 : s];
                int2 r1 = stag[j1 < e ? j1 : s];
                float w0 = (j0 < e) ? __int_as_float(r0.y) : 0.f;
                float w1 = (j1 < e) ? __int_as_float(r1.y) : 0.f;
                int2 q0 = *(const int2*)(hb + ((unsigned)r0.x + c4b));
                int2 q1 = *(const int2*)(hb + ((unsigned)r1.x + c4b));
                ACC2(q0, w0);
                ACC2(q1, w1);
            }
            float acc[4] = {a01[0], a01[1], a23[0], a23[1]};
#pragma unroll
            for (int k = 0; k < 4; ++k) {
                float v = acc[k];
                v += __shfl_xor(v, 16, 64);
                v += __shfl_xor(v, 32, 64);
                acc[k] = v;
            }
            if (g == 0) {
                float di = dinv[n];
                int2 qs = *(const int2*)(hb + (((size_t)(unsigned)n << 7) + c4b));
                float4 b = *(const float4*)(bconv + hh * 64 + c4);
                unsigned ux = (unsigned)qs.x, uy = (unsigned)qs.y;
                bf16x4 o;
                o[0] = (short)f2bf(fmaxf(di * (acc[0] + __uint_as_float(ux << 16)) + b.x, 0.f));
                o[1] = (short)f2bf(fmaxf(di * (acc[1] + __uint_as_float(ux & 0xFFFF0000u)) + b.y, 0.f));
                o[2] = (short)f2bf(fmaxf(di * (acc[2] + __uint_as_float(uy << 16)) + b.z, 0.f));
                o[3] = (short)f2bf(fmaxf(di * (acc[3] + __uint_as_float(uy & 0xFFFF0000u)) + b.w, 0.f));
                *(bf16x4*)(h2 + (size_t)n * 128 + hh * 64 + c4) = o;
            }
        }
    }
#undef ACC2
}

// ---- gemm23: out = relu(h2 @ Wf^T + bf) @ W2^T + b2, intermediate staged in LDS ----
__global__ __launch_bounds__(256) void gemm23_k(const unsigned short* __restrict__ h2,
                                                const unsigned short* __restrict__ Wfb,
                                                const float* __restrict__ bfc,
                                                const unsigned short* __restrict__ W2b,
                                                const float* __restrict__ b2,
                                                float* __restrict__ out, int M) {
    __shared__ __align__(16) unsigned short Wl[128 * 136];
    __shared__ __align__(16) unsigned short Tl[64 * 136];
    const int tid = threadIdx.x;

    // stage Wfb (bf16 dense) -> Wl (136-stride)
#pragma unroll
    for (int i = 0; i < 8; ++i) {
        int c = i * 256 + tid;
        int r = c >> 4, col = (c & 15) * 8;
        *(bf16x8*)&Wl[r * 136 + col] = *(const bf16x8*)(Wfb + c * 8);
    }
    __syncthreads();

    const int wave = tid >> 6, lane = tid & 63;
    const int m = lane & 15, quad = lane >> 4;
    const int rowBase = blockIdx.x * 64 + wave * 16;
    int arow = rowBase + m;
    int arowc = arow < M ? arow : (M - 1);

    bf16x8 afrag[4];
    {
        const unsigned short* pa = h2 + (size_t)arowc * 128 + quad * 8;
#pragma unroll
        for (int kc = 0; kc < 4; ++kc)
            afrag[kc] = *(const bf16x8*)(pa + kc * 32);
    }

    // stage 1: T = bf16(relu(h2 @ Wf^T + bf)) -> LDS
#pragma unroll
    for (int nt = 0; nt < 8; ++nt) {
        f32x4 acc = {0.f, 0.f, 0.f, 0.f};
        const unsigned short* wb = &Wl[(nt * 16 + m) * 136 + quad * 8];
#pragma unroll
        for (int kc = 0; kc < 4; ++kc) {
            bf16x8 bfrag = *(const bf16x8*)(wb + kc * 32);
            acc = __builtin_amdgcn_mfma_f32_16x16x32_bf16(afrag[kc], bfrag, acc, 0, 0, 0);
        }
        const int col = nt * 16 + m;
        float bv = bfc[col];
#pragma unroll
        for (int r = 0; r < 4; ++r) {
            int rowl = wave * 16 + quad * 4 + r;
            Tl[rowl * 136 + col] = f2bf(fmaxf(acc[r] + bv, 0.f));
        }
    }
    __syncthreads();

    // stage W2b (overwrite Wl)
#pragma unroll
    for (int i = 0; i < 8; ++i) {
        int c = i * 256 + tid;
        int r = c >> 4, col = (c & 15) * 8;
        *(bf16x8*)&Wl[r * 136 + col] = *(const bf16x8*)(W2b + c * 8);
    }
    __syncthreads();

    // stage 2: out = T @ W2^T + b2
    bf16x8 afrag2[4];
    {
        const unsigned short* pa = &Tl[(wave * 16 + m) * 136 + quad * 8];
#pragma unroll
        for (int kc = 0; kc < 4; ++kc)
            afrag2[kc] = *(const bf16x8*)(pa + kc * 32);
    }
#pragma unroll
    for (int nt = 0; nt < 8; ++nt) {
        f32x4 acc = {0.f, 0.f, 0.f, 0.f};
        const unsigned short* wb = &Wl[(nt * 16 + m) * 136 + quad * 8];
#pragma unroll
        for (int kc = 0; kc < 4; ++kc) {
            bf16x8 bfrag = *(const bf16x8*)(wb + kc * 32);
            acc = __builtin_amdgcn_mfma_f32_16x16x32_bf16(afrag2[kc], bfrag, acc, 0, 0, 0);
        }
        const int col = nt * 16 + m;
        float bv = b2[col];
#pragma unroll
        for (int r = 0; r < 4; ++r) {
            int row = rowBase + quad * 4 + r;
            if (row < M)
                out[(size_t)row * 128 + col] = acc[r] + bv;
        }
    }
}

extern "C" void kernel_launch(void* const* d_in, const int* in_sizes, int n_in,
                              void* d_out, int out_size, void* d_ws, size_t ws_size,
                              hipStream_t stream) {
    const float* x  = (const float*)d_in[0];
    const int* ei   = (const int*)d_in[1];
    const float* ew = (const float*)d_in[2];
    const float* Wc = (const float*)d_in[3];
    const float* bc = (const float*)d_in[4];
    const float* Wf = (const float*)d_in[5];
    const float* bf = (const float*)d_in[6];
    const float* W2 = (const float*)d_in[7];
    const float* b2 = (const float*)d_in[8];
    float* out = (float*)d_out;

    const int N = in_sizes[0] / 128;
    const int E = in_sizes[2];
    const int P = (N + PS - 1) / PS;     // 3125
    const int NBK = (N + 511) >> 9;      // 196 buckets of 16 partitions

    auto align256 = [](size_t v) { return (v + 255) & ~(size_t)255; };
    char* ws = (char*)d_ws;
    size_t off = 0;
    float* dinv  = (float*)(ws + off); off += align256((size_t)N * 4);
    int* nodeOff = (int*)(ws + off);   off += align256((size_t)N * 4);
    int* partCnt = (int*)(ws + off);   off += align256((size_t)P * 4);
    int* bucketCnt = (int*)(ws + off); off += align256((size_t)NBK * 4);
    unsigned short* wcb = (unsigned short*)(ws + off); off += align256(16384 * 2);
    unsigned short* wfb = (unsigned short*)(ws + off); off += align256(16384 * 2);
    unsigned short* w2b = (unsigned short*)(ws + off); off += align256(16384 * 2);
    unsigned short* h  = (unsigned short*)(ws + off); off += (size_t)N * 256;  // h'[2][N][64] channel-split
    unsigned short* h2 = (unsigned short*)(ws + off);

    // bstage (NBK*CAPB*8B = 27.5MB) aliases [h, h2]: consumed by scatB before
    // dgemm1 writes h.
    int2* bstage = (int2*)h;

    // d_out scratch: partition regions P*CAPP*8B = 32.8MB <= 51.2MB,
    // consumed by aggF before gemm23 rewrites d_out.
    int2* regions = (int2*)out;

    const int EPB = (E + NB - 1) / NB;

    hipMemsetAsync(bucketCnt, 0, (size_t)NBK * 4, stream);
    scatA_k<<<NB, 1024, 0, stream>>>(ei, ew, bucketCnt, bstage, Wc, Wf, W2, wcb, wfb, w2b, E, NBK, EPB);
    scatB_k<<<NBK, 1024, 0, stream>>>(bucketCnt, bstage, partCnt, nodeOff, dinv, regions, P, N);
    dgemm1_k<<<(N + 63) / 64, 256, 0, stream>>>(x, wcb, dinv, h, N);
    aggF_k<<<P, 256, 0, stream>>>(partCnt, nodeOff, regions, h, dinv, bc, h2, N);
    gemm23_k<<<(N + 63) / 64, 256, 0, stream>>>(h2, wfb, bf, w2b, b2, out, N);
}